// Round 11
// baseline (245.655 us; speedup 1.0000x reference)
//
#include <hip/hip_runtime.h>
#include <hip/hip_bf16.h>
#include <stdint.h>

#define BATCH 2
#define HEADS 16
#define BH    32
#define SEQ   2048
#define DIM   128
#define ELEMS (BATCH*HEADS*SEQ*DIM)   // 8388608 per tensor

#define KVB   64
#define NT    (SEQ/KVB)               // 32 tiles

using f32x4  = __attribute__((ext_vector_type(4))) float;
using f32x16 = __attribute__((ext_vector_type(16))) float;
using bf16x8 = __attribute__((ext_vector_type(8))) short;
using us4    = __attribute__((ext_vector_type(4))) unsigned short;
using ui2    = __attribute__((ext_vector_type(2))) unsigned int;

__device__ __forceinline__ unsigned short f2bf(float f) {
    union { float f; uint32_t u; } v; v.f = f;
    uint32_t u = v.u;
    uint32_t r = u + 0x7FFFu + ((u >> 16) & 1u);   // RNE
    return (unsigned short)(r >> 16);
}

__device__ __forceinline__ uint32_t packbf2(float lo, float hi) {
    __hip_bfloat162 h2 = __float22bfloat162_rn(make_float2(lo, hi));
    union { __hip_bfloat162 h; uint32_t u; } c; c.h = h2;
    return c.u;   // low16 = lo, high16 = hi
}

// ---- fused prep ----
// blocks [0,2048):    Q fp32 -> bf16, pre-scaled by 1/sqrt(d)*log2(e)
// blocks [2048,4096): K fp32 -> bf16
// blocks [4096,6144): V fp32 [bh][n][d] -> VT bf16 [bh][d][n]
__global__ __launch_bounds__(256) void prep(const float* __restrict__ Q,
                                            const float* __restrict__ K,
                                            const float* __restrict__ V,
                                            unsigned short* __restrict__ qb,
                                            unsigned short* __restrict__ kb,
                                            unsigned short* __restrict__ vt) {
    const int b = blockIdx.x, t = threadIdx.x;
    const float scl = 0.08838834764831845f * 1.4426950408889634f;
    if (b < 4096) {
        const bool isQ = b < 2048;
        const float* src = isQ ? Q : K;
        unsigned short* dst = isQ ? qb : kb;
        const float f = isQ ? scl : 1.0f;
        size_t base = (size_t)(isQ ? b : b - 2048) * 4096 + t * 4;
        #pragma unroll
        for (int j = 0; j < 4; ++j) {
            f32x4 v = *(const f32x4*)(src + base + j * 1024);
            us4 o;
            #pragma unroll
            for (int jj = 0; jj < 4; ++jj) o[jj] = f2bf(v[jj] * f);
            *(us4*)(dst + base + j * 1024) = o;
        }
    } else {
        __shared__ unsigned short tile[64][66];
        const int b2 = b - 4096;
        const int bh = b2 >> 6, rem = b2 & 63;
        const int n0 = (rem >> 1) * 64, d0 = (rem & 1) * 64;
        const int rr = t >> 4, cc = t & 15;
        #pragma unroll
        for (int j = 0; j < 4; ++j) {
            int row = rr + 16 * j;
            f32x4 v = *(const f32x4*)(V + ((size_t)bh * SEQ + n0 + row) * DIM + d0 + cc * 4);
            #pragma unroll
            for (int jj = 0; jj < 4; ++jj) tile[row][cc * 4 + jj] = f2bf(v[jj]);
        }
        __syncthreads();
        #pragma unroll
        for (int j = 0; j < 4; ++j) {
            int drow = rr + 16 * j;
            us4 o;
            #pragma unroll
            for (int jj = 0; jj < 4; ++jj) o[jj] = tile[cc * 4 + jj][drow];
            *(us4*)(vt + ((size_t)bh * DIM + d0 + drow) * SEQ + n0 + cc * 4) = o;
        }
    }
}

// ---- flash attention: 8 waves (4 q-subtiles x 2 kv-halves), KVB=64 ----
// 512-thread blocks share one 64KB K/V double-buffer -> 16 waves/CU (4/SIMD),
// 2x the TLP of the 4-wave variant at the same grid of 512 blocks.
// Wave (qsub, h): QBLK=32 rows, kv rows 32h..32h+31 of each tile; partial
// flash state per wave, pair-merged through LDS once at the end.
__global__ __launch_bounds__(512, 4) void attn_fwd(const unsigned short* __restrict__ Qb,
                                                   const unsigned short* __restrict__ Kb,
                                                   const unsigned short* __restrict__ VTb,
                                                   float* __restrict__ Out) {
    __shared__ __attribute__((aligned(16))) char smem[65536];

    const int bid  = blockIdx.x;
    const int xcd  = bid & 7;
    const int slot = bid >> 3;
    const int head = xcd * 4 + (slot >> 4);    // bijective: 512 = 8 XCD x 4 heads x 16 qtiles
    const int wid  = threadIdx.x >> 6;         // 0..7
    const int qsub = wid >> 1;                 // 0..3
    const int h    = wid & 1;                  // kv half
    const int lane = threadIdx.x & 63;
    const int l31  = lane & 31;
    const int hL   = lane >> 5;
    const int q0   = (slot & 15) * 128 + qsub * 32;

    const unsigned short* Qh = Qb + (size_t)head * SEQ * DIM;
    const char* KhB  = (const char*)(Kb  + (size_t)head * SEQ * DIM);
    const char* VThB = (const char*)(VTb + (size_t)head * DIM * SEQ);

    // Q B-frags (bf16, pre-scaled in prep): lane holds Q[q0+l31][16u + 8hL .. +7]
    bf16x8 qf[8];
    {
        const char* qrow = (const char*)(Qh + (size_t)(q0 + l31) * DIM) + 16 * hL;
        #pragma unroll
        for (int u = 0; u < 8; ++u) qf[u] = *(const bf16x8*)(qrow + 32 * u);
    }

    f32x16 acc[4];
    #pragma unroll
    for (int m = 0; m < 4; ++m) acc[m] = (f32x16)(0.f);
    float m_run = -INFINITY, l_run = 0.f;

    const int swzK = (l31 & 15) << 4;          // K read swizzle
    const int swzV = ((l31 >> 1) & 7) << 4;    // VT read swizzle (row-pair)

    // stage one KV tile (K 16KB: 16 segs; VT 16KB: 16 segs); 8 waves x (2K+2V)
    auto STAGE = [&](int buf, int kv0) {
        #pragma unroll
        for (int i = 0; i < 2; ++i) {
            int seg = wid * 2 + i;                    // 0..15
            int r   = seg * 4 + (lane >> 4);          // K row 0..63
            int cb  = ((lane & 15) << 4) ^ ((r & 15) << 4);
            const char* g = KhB + (((size_t)(kv0 + r)) << 8) + cb;
            __builtin_amdgcn_global_load_lds(
                (const __attribute__((address_space(1))) void*)g,
                (__attribute__((address_space(3))) void*)(smem + buf * 16384 + seg * 1024),
                16, 0, 0);
        }
        #pragma unroll
        for (int i = 0; i < 2; ++i) {
            int seg = wid * 2 + i;                    // 0..15
            int rp  = seg * 4 + (lane >> 4);          // d-rowpair 0..63
            int q8  = (lane & 15) << 4;
            int pre = q8 ^ ((rp & 7) << 4);
            int r   = 2 * rp + (pre >> 7);            // VT d-row 0..127
            int cb  = pre & 127;
            const char* g = VThB + (size_t)r * (SEQ * 2) + ((size_t)kv0 << 1) + cb;
            __builtin_amdgcn_global_load_lds(
                (const __attribute__((address_space(1))) void*)g,
                (__attribute__((address_space(3))) void*)(smem + 32768 + buf * 16384 + seg * 1024),
                16, 0, 0);
        }
    };

    STAGE(0, 0);

    #pragma unroll 1
    for (int t = 0; t < NT; ++t) {
        const int cur = t & 1;
        if (t + 1 < NT) {
            STAGE(cur ^ 1, (t + 1) * KVB);
            asm volatile("s_waitcnt vmcnt(4)" ::: "memory");  // drain tile t; t+1 in flight
        } else {
            asm volatile("s_waitcnt vmcnt(0)" ::: "memory");
        }
        __builtin_amdgcn_s_barrier();
        asm volatile("" ::: "memory");

        const char* kb = smem + cur * 16384;
        const char* vb = smem + 32768 + cur * 16384;

        // ---- QK^T: S^T[kv-half][q], one 32x32 tile per wave ----
        f32x16 s0 = (f32x16)(0.f);
        {
            const char* krow = kb + (size_t)(32 * h + l31) * 256;
            #pragma unroll
            for (int u = 0; u < 8; ++u) {
                int cb = (32 * u + 16 * hL) ^ swzK;
                bf16x8 k0 = *(const bf16x8*)(krow + cb);
                s0 = __builtin_amdgcn_mfma_f32_32x32x16_bf16(k0, qf[u], s0, 0, 0, 0);
            }
        }

        // ---- partial online softmax (16 scores/lane) ----
        float smax = -1e30f;
        #pragma unroll
        for (int r = 0; r < 16; ++r) smax = fmaxf(smax, s0[r]);
        smax = fmaxf(smax, __shfl_xor(smax, 32));

        if (!__all(smax - m_run <= 8.f)) {          // defer-max (T13)
            float mnew = fmaxf(m_run, smax);
            float corr = __builtin_amdgcn_exp2f(m_run - mnew);
            #pragma unroll
            for (int m = 0; m < 4; ++m) acc[m] *= corr;
            l_run *= corr;
            m_run = mnew;
        }

        float ps[4] = {0.f, 0.f, 0.f, 0.f};
        #pragma unroll
        for (int r = 0; r < 16; ++r) {
            s0[r] = __builtin_amdgcn_exp2f(s0[r] - m_run);
            ps[r & 3] += s0[r];
        }
        l_run += (ps[0] + ps[1]) + (ps[2] + ps[3]);

        // ---- pack P to bf16 dword pairs ----
        uint32_t w0[8];
        #pragma unroll
        for (int k2 = 0; k2 < 8; ++k2)
            w0[k2] = packbf2(s0[2 * k2], s0[2 * k2 + 1]);

        // ---- PV over kv-half: O^T[d][q] += V^T * P^T ----
        #pragma unroll
        for (int ss = 0; ss < 2; ++ss) {
            ui2 r02 = __builtin_amdgcn_permlane32_swap(w0[4 * ss],     w0[4 * ss + 2], false, false);
            ui2 r13 = __builtin_amdgcn_permlane32_swap(w0[4 * ss + 1], w0[4 * ss + 3], false, false);
            union { uint32_t u[4]; bf16x8 v; } Bf;
            Bf.u[0] = r02[0];
            Bf.u[1] = r13[0];
            Bf.u[2] = r02[1];
            Bf.u[3] = r13[1];
            const int cbv = (32 * (2 * h + ss) + 16 * hL) + ((l31 & 1) << 7);
            #pragma unroll
            for (int m = 0; m < 4; ++m) {
                int rp = 16 * m + (l31 >> 1);
                bf16x8 vf = *(const bf16x8*)(vb + (size_t)rp * 256 + (cbv ^ swzV));
                acc[m] = __builtin_amdgcn_mfma_f32_32x32x16_bf16(vf, Bf.v, acc[m], 0, 0, 0);
            }
        }

        asm volatile("" ::: "memory");
        __builtin_amdgcn_s_barrier();
    }

    // ---- pair merge: wave (qsub,1) state folded into wave (qsub,0) ----
    l_run += __shfl_xor(l_run, 32);               // per-q-column l (pair lanes)
    __syncthreads();
    float* mlp = (float*)smem;                    // 4KB: [qsub][lane][m,l]
    if (h == 1) {
        mlp[(qsub * 64 + lane) * 2]     = m_run;
        mlp[(qsub * 64 + lane) * 2 + 1] = l_run;
    }
    __syncthreads();
    float sB = 0.f;
    if (h == 0) {
        float mB = mlp[(qsub * 64 + lane) * 2];
        float lB = mlp[(qsub * 64 + lane) * 2 + 1];
        float mN = fmaxf(m_run, mB);
        float sA = __builtin_amdgcn_exp2f(m_run - mN);
        sB       = __builtin_amdgcn_exp2f(mB - mN);
        l_run = sA * l_run + sB * lB;
        #pragma unroll
        for (int m = 0; m < 4; ++m) acc[m] *= sA;
    }
    __syncthreads();   // A done reading ml before B overwrites region with acc
    {
        char* accr = smem + qsub * 16384;         // 16KB per qsub
        if (h == 1) {
            #pragma unroll
            for (int m = 0; m < 4; ++m)
                #pragma unroll
                for (int c = 0; c < 4; ++c) {
                    int cidx = m * 4 + c;
                    f32x4 v = { acc[m][4*c], acc[m][4*c+1], acc[m][4*c+2], acc[m][4*c+3] };
                    *(f32x4*)(accr + lane * 256 + (((cidx ^ (lane & 15)) & 15) << 4)) = v;
                }
        }
        __syncthreads();
        if (h == 0) {
            #pragma unroll
            for (int m = 0; m < 4; ++m)
                #pragma unroll
                for (int c = 0; c < 4; ++c) {
                    int cidx = m * 4 + c;
                    f32x4 v = *(const f32x4*)(accr + lane * 256 + (((cidx ^ (lane & 15)) & 15) << 4));
                    #pragma unroll
                    for (int j = 0; j < 4; ++j) acc[m][4*c+j] += sB * v[j];
                }
        }
    }
    __syncthreads();

    // ---- epilogue (h==0 waves): normalize, swizzled LDS transpose, store ----
    const float inv = 1.0f / l_run;
    float* ob = (float*)(smem + qsub * 16384);    // 32 q-rows x 128 f32, swizzled
    if (h == 0) {
        #pragma unroll
        for (int m = 0; m < 4; ++m) {
            #pragma unroll
            for (int r = 0; r < 16; ++r) {
                int d = 32 * m + (r & 3) + 8 * (r >> 2) + 4 * hL;
                ob[l31 * 128 + (d ^ ((l31 & 7) << 2))] = acc[m][r] * inv;
            }
        }
    }
    __syncthreads();
    if (h == 0) {
        float* outp = Out + ((size_t)head * SEQ + q0) * DIM;
        #pragma unroll
        for (int i = 0; i < 16; ++i) {
            int row = 2 * i + hL;
            f32x4 v = *(const f32x4*)(ob + row * 128 + ((4 * l31) ^ ((row & 7) << 2)));
            *(f32x4*)(outp + (size_t)row * DIM + 4 * l31) = v;
        }
    }
}

extern "C" void kernel_launch(void* const* d_in, const int* in_sizes, int n_in,
                              void* d_out, int out_size, void* d_ws, size_t ws_size,
                              hipStream_t stream) {
    (void)in_sizes; (void)n_in; (void)out_size;
    const float* q = (const float*)d_in[0];
    const float* k = (const float*)d_in[1];
    const float* v = (const float*)d_in[2];
    float* out = (float*)d_out;

    const size_t needed = (size_t)ELEMS * 2 * 3;
    if (ws_size < needed) return;

    unsigned short* qb = (unsigned short*)d_ws;
    unsigned short* kb = qb + ELEMS;
    unsigned short* vt = kb + ELEMS;

    prep<<<6144, 256, 0, stream>>>(q, k, v, qb, kb, vt);
    attn_fwd<<<512, 512, 0, stream>>>(qb, kb, vt, out);
}